// Round 5
// baseline (106.296 us; speedup 1.0000x reference)
//
#include <hip/hip_runtime.h>
#include <hip/hip_bf16.h>

// SelfAttentionBlock collapses algebraically:
//   softmax rows sum to 1; einsum('btu,btj->btj', w, v) = (sum_u w)·v = v
//   =>  out = x @ Wv^T + bv.   M=8192, K=1024, N=64.
// Inputs fp32 (round-1 NaN proved bf16-misread). OUTPUT IS FP32 — rounds 0-4
// wrote bf16 into the fp32 d_out; the 6.5625 absmax matched the
// "bf16-pair-read-as-float" statistics exactly. Fixed here.

#define K_DIM 1024
#define N_DIM 64

typedef __attribute__((ext_vector_type(4))) float f32x4;
typedef __attribute__((ext_vector_type(8))) short s16x8;   // 8 bf16 frag
typedef __attribute__((ext_vector_type(4))) short s16x4;

__device__ __forceinline__ short f2bf(float f) {
    // round-to-nearest-even fp32 -> bf16 (inputs finite)
    union { float f; unsigned u; } v{f};
    unsigned r = v.u + 0x7FFFu + ((v.u >> 16) & 1u);
    return (short)(r >> 16);
}
__device__ __forceinline__ float bf2f(short s) {
    union { unsigned u; float f; } v;
    v.u = ((unsigned)(unsigned short)s) << 16;
    return v.f;
}

// ---- Pre-pass: Wv fp32 [64][1024] -> bf16 in d_ws ----------------------
__global__ __launch_bounds__(256) void cvt_w_kernel(
    const float* __restrict__ w, short* __restrict__ o) {
    const int i = (blockIdx.x * 256 + threadIdx.x) * 4;   // 64 blocks -> 65536
    f32x4 v = *(const f32x4*)(w + i);
    s16x4 r;
#pragma unroll
    for (int j = 0; j < 4; ++j) r[j] = f2bf(v[j]);
    *(s16x4*)(o + i) = r;
}

// ---- Probe: verify MFMA fragment mapping on real data ------------------
// h = 2*kmap + placement;  kmap: 0=contig k=8q+j, 1=split k=(j>>2)*16+4q+(j&3)
// placement: 0 => D(row=4q+reg, col=l16), 1 => transposed.  -1 = no match.
__global__ __launch_bounds__(64) void probe_kernel(
    const float* __restrict__ x, const float* __restrict__ wv,
    int* __restrict__ sel) {
    __shared__ short xb[16][32];
    __shared__ short wb[16][32];
    const int lane = threadIdx.x;
    for (int idx = lane; idx < 16 * 32; idx += 64) {
        const int r = idx >> 5, k = idx & 31;
        xb[r][k] = f2bf(x[r * K_DIM + k]);
        wb[r][k] = f2bf(wv[r * K_DIM + k]);
    }
    __syncthreads();
    const int quad = lane >> 4, l16 = lane & 15;

    s16x8 ac, as_, bc, bs;
#pragma unroll
    for (int j = 0; j < 8; ++j) { ac[j] = xb[l16][quad * 8 + j];
                                  bc[j] = wb[l16][quad * 8 + j]; }
#pragma unroll
    for (int j = 0; j < 4; ++j) {
        as_[j]     = xb[l16][quad * 4 + j];
        as_[4 + j] = xb[l16][16 + quad * 4 + j];
        bs[j]      = wb[l16][quad * 4 + j];
        bs[4 + j]  = wb[l16][16 + quad * 4 + j];
    }
    const f32x4 z = {0.f, 0.f, 0.f, 0.f};
    f32x4 P0 = __builtin_amdgcn_mfma_f32_16x16x32_bf16(ac,  bc, z, 0, 0, 0);
    f32x4 P1 = __builtin_amdgcn_mfma_f32_16x16x32_bf16(as_, bs, z, 0, 0, 0);

    int h = -1;
#pragma unroll
    for (int km = 0; km < 2; ++km) {
        f32x4 P = km ? P1 : P0;
#pragma unroll
        for (int p = 0; p < 2; ++p) {
            bool ok = true;
#pragma unroll
            for (int r = 0; r < 4; ++r) {
                const int row = (p == 0) ? (quad * 4 + r) : l16;
                const int col = (p == 0) ? l16 : (quad * 4 + r);
                float t = 0.f;
                for (int k = 0; k < 32; ++k)
                    t += bf2f(xb[row][k]) * bf2f(wb[col][k]);
                ok = ok && (fabsf(P[r] - t) < 1e-3f);
            }
            if ((__ballot(ok) == ~0ull) && h < 0) h = km * 2 + p;
        }
    }
    if (lane == 0) sel[0] = h;
}

// ---- Main: v = x @ Wv^T + bv, 512 blocks x 256 thr, split-K=4 ----------
__global__ __launch_bounds__(256, 2) void vproj_kernel(
    const float* __restrict__ x,               // [8192][1024] fp32
    const short* __restrict__ wbf,             // [64][1024] bf16
    const float* __restrict__ bv,              // [64] fp32
    const int* __restrict__ sel,               // mapping selector from probe
    float* __restrict__ out)                   // [8192][64] FP32
{
    const int hs = sel[0];
    const int h  = (hs < 0) ? 0 : hs;
    const int km = h >> 1, p = h & 1;

    const int tid  = threadIdx.x;
    const int wave = tid >> 6;
    const int lane = tid & 63;
    const int quad = lane >> 4;
    const int l16  = lane & 15;

    const int mt  = blockIdx.x;
    const int row = (mt << 4) + l16;

    const int offA0 = km ? (quad << 2) : (quad << 3);
    const int offA1 = offA0 + (km ? 16 : 4);

    const int kb = wave << 8;                  // this wave's 256-K chunk
    const float* ap  = x   + row * K_DIM + kb;
    const short* bp0 = wbf + (l16     ) * K_DIM + kb;
    const short* bp1 = wbf + (l16 + 16) * K_DIM + kb;
    const short* bp2 = wbf + (l16 + 32) * K_DIM + kb;
    const short* bp3 = wbf + (l16 + 48) * K_DIM + kb;

    f32x4 acc0 = {0.f, 0.f, 0.f, 0.f};
    f32x4 acc1 = acc0, acc2 = acc0, acc3 = acc0;

#pragma unroll
    for (int ks = 0; ks < 8; ++ks) {
        const int o0 = ks * 32 + offA0;
        const int o1 = ks * 32 + offA1;
        f32x4 a0 = *(const f32x4*)(ap + o0);
        f32x4 a1 = *(const f32x4*)(ap + o1);
        s16x4 b0l = *(const s16x4*)(bp0 + o0), b0h = *(const s16x4*)(bp0 + o1);
        s16x4 b1l = *(const s16x4*)(bp1 + o0), b1h = *(const s16x4*)(bp1 + o1);
        s16x4 b2l = *(const s16x4*)(bp2 + o0), b2h = *(const s16x4*)(bp2 + o1);
        s16x4 b3l = *(const s16x4*)(bp3 + o0), b3h = *(const s16x4*)(bp3 + o1);
        s16x8 a, b0, b1, b2, b3;
#pragma unroll
        for (int j = 0; j < 4; ++j) {
            a[j] = f2bf(a0[j]); a[4 + j] = f2bf(a1[j]);
            b0[j] = b0l[j]; b0[4 + j] = b0h[j];
            b1[j] = b1l[j]; b1[4 + j] = b1h[j];
            b2[j] = b2l[j]; b2[4 + j] = b2h[j];
            b3[j] = b3l[j]; b3[4 + j] = b3h[j];
        }
        acc0 = __builtin_amdgcn_mfma_f32_16x16x32_bf16(a, b0, acc0, 0, 0, 0);
        acc1 = __builtin_amdgcn_mfma_f32_16x16x32_bf16(a, b1, acc1, 0, 0, 0);
        acc2 = __builtin_amdgcn_mfma_f32_16x16x32_bf16(a, b2, acc2, 0, 0, 0);
        acc3 = __builtin_amdgcn_mfma_f32_16x16x32_bf16(a, b3, acc3, 0, 0, 0);
    }

    __shared__ float red[4][16][N_DIM + 1];
    const int r0 = quad << 2;
    if (p == 0) {
#pragma unroll
        for (int r = 0; r < 4; ++r) {
            red[wave][r0 + r][l16     ] = acc0[r];
            red[wave][r0 + r][l16 + 16] = acc1[r];
            red[wave][r0 + r][l16 + 32] = acc2[r];
            red[wave][r0 + r][l16 + 48] = acc3[r];
        }
    } else {
#pragma unroll
        for (int r = 0; r < 4; ++r) {
            red[wave][l16][r0 + r     ] = acc0[r];
            red[wave][l16][r0 + r + 16] = acc1[r];
            red[wave][l16][r0 + r + 32] = acc2[r];
            red[wave][l16][r0 + r + 48] = acc3[r];
        }
    }
    __syncthreads();

    const int c   = tid & 63;                 // output col, coalesced store
    const int rr0 = tid >> 6;                 // rows rr0, rr0+4, rr0+8, rr0+12
    const float bias = bv[c];
#pragma unroll
    for (int i = 0; i < 4; ++i) {
        const int r = rr0 + (i << 2);
        const float s = red[0][r][c] + red[1][r][c] + red[2][r][c]
                      + red[3][r][c] + bias;
        out[((mt << 4) + r) * N_DIM + c] = s;   // FP32 store
    }
}

// ---- Emergency fallback: pure-VALU fp32 GEMM; runs only if probe failed.
__global__ __launch_bounds__(256) void fallback_kernel(
    const float* __restrict__ x, const float* __restrict__ wv,
    const float* __restrict__ bv, const int* __restrict__ sel,
    float* __restrict__ out) {
    if (sel[0] >= 0) return;                   // probe succeeded: no-op
    const int mt = blockIdx.x;
#pragma unroll
    for (int i = 0; i < 4; ++i) {
        const int idx = threadIdx.x + (i << 8);          // 0..1023
        const int r = idx >> 6, c = idx & 63;
        const float* xr = x  + ((mt << 4) + r) * K_DIM;
        const float* wr = wv + c * K_DIM;
        float s = 0.f;
        for (int k = 0; k < K_DIM; k += 4) {
            f32x4 xa = *(const f32x4*)(xr + k);
            f32x4 wa = *(const f32x4*)(wr + k);
            s += xa[0]*wa[0] + xa[1]*wa[1] + xa[2]*wa[2] + xa[3]*wa[3];
        }
        out[((mt << 4) + r) * N_DIM + c] = s + bv[c];
    }
}

extern "C" void kernel_launch(void* const* d_in, const int* in_sizes, int n_in,
                              void* d_out, int out_size, void* d_ws, size_t ws_size,
                              hipStream_t stream) {
    // dict order: 0:x 1:Wq 2:bq 3:Wk 4:bk 5:Wv 6:bv (size-checked fallback).
    int ix = 0, iw = -1, ib = -1;
    for (int i = 0; i < n_in; ++i) {
        if      (in_sizes[i] == 8388608) ix = i;
        else if (in_sizes[i] == 65536)   iw = i;   // keeps last (= Wv)
        else if (in_sizes[i] == 64)      ib = i;   // keeps last (= bv)
    }
    if (iw < 0) iw = 5;
    if (ib < 0) ib = 6;

    const float* x  = (const float*)d_in[ix];
    const float* Wv = (const float*)d_in[iw];
    const float* bv = (const float*)d_in[ib];
    short* wbf = (short*)d_ws;                                // 128 KB
    int*   sel = (int*)((char*)d_ws + 65536 * sizeof(short)); // +4 B
    float* out = (float*)d_out;                               // FP32 output

    cvt_w_kernel<<<64, 256, 0, stream>>>(Wv, wbf);
    probe_kernel<<<1, 64, 0, stream>>>(x, Wv, sel);
    vproj_kernel<<<512, 256, 0, stream>>>(x, wbf, bv, sel, out);
    fallback_kernel<<<512, 256, 0, stream>>>(x, Wv, bv, sel, out);
}

// Round 6
// 92.622 us; speedup vs baseline: 1.1476x; 1.1476x over previous
//
#include <hip/hip_runtime.h>
#include <hip/hip_bf16.h>

// SelfAttentionBlock collapses algebraically:
//   softmax rows sum to 1; einsum('btu,btj->btj', w, v) = (sum_u w)·v = v
//   =>  out = x @ Wv^T + bv.   M=8192, K=1024, N=64. fp32 in, FP32 out.
//
// History: round-1 NaN proved inputs are fp32 (not bf16); round-5 PASS
// (absmax 0.03125) proved output is fp32 and the documented MFMA mapping
// (h=0: A/B frag k = quad*8+j contiguous; C/D row=quad*4+reg, col=lane&15)
// is correct — the runtime probe always selected it, so it's hardcoded now.

#define K_DIM 1024
#define N_DIM 64

typedef __attribute__((ext_vector_type(4))) float f32x4;
typedef __attribute__((ext_vector_type(8))) short s16x8;   // 8 bf16 frag
typedef __attribute__((ext_vector_type(4))) short s16x4;

__device__ __forceinline__ short f2bf(float f) {
    // round-to-nearest-even fp32 -> bf16 (inputs finite)
    union { float f; unsigned u; } v{f};
    unsigned r = v.u + 0x7FFFu + ((v.u >> 16) & 1u);
    return (short)(r >> 16);
}

// ---- Pre-pass: Wv fp32 [64][1024] -> bf16 in d_ws (L2-resident, 128 KB).
__global__ __launch_bounds__(256) void cvt_w_kernel(
    const float* __restrict__ w, short* __restrict__ o) {
    const int i = (blockIdx.x * 256 + threadIdx.x) * 4;   // 64 blocks -> 65536
    f32x4 v = *(const f32x4*)(w + i);
    s16x4 r;
#pragma unroll
    for (int j = 0; j < 4; ++j) r[j] = f2bf(v[j]);
    *(s16x4*)(o + i) = r;
}

// ---- Main: v = x @ Wv^T + bv. 512 blocks x 256 thr; block = 16-row
// M-tile; split-K=4 across the 4 waves (256 K each); LDS cross-wave reduce.
__global__ __launch_bounds__(256, 2) void vproj_kernel(
    const float* __restrict__ x,               // [8192][1024] fp32
    const short* __restrict__ wbf,             // [64][1024] bf16
    const float* __restrict__ bv,              // [64] fp32
    float* __restrict__ out)                   // [8192][64] fp32
{
    const int tid  = threadIdx.x;
    const int wave = tid >> 6;        // 0..3 — K-chunk owner
    const int lane = tid & 63;
    const int quad = lane >> 4;       // 0..3
    const int l16  = lane & 15;

    const int mt  = blockIdx.x;               // 0..511
    const int row = (mt << 4) + l16;          // A row m = lane&15

    // A frag element j = x[row][kb + j] (contiguous 8); B: Wv[l16+16t][same].
    const int kb = (wave << 8) + (quad << 3);

    const float* ap  = x   + row * K_DIM + kb;
    const short* bp0 = wbf + (l16     ) * K_DIM + kb;
    const short* bp1 = wbf + (l16 + 16) * K_DIM + kb;
    const short* bp2 = wbf + (l16 + 32) * K_DIM + kb;
    const short* bp3 = wbf + (l16 + 48) * K_DIM + kb;

    f32x4 acc0 = {0.f, 0.f, 0.f, 0.f};
    f32x4 acc1 = acc0, acc2 = acc0, acc3 = acc0;

#pragma unroll
    for (int ks = 0; ks < 8; ++ks) {
        const int o = ks * 32;                 // 32 K-elements per MFMA step
        f32x4 a0 = *(const f32x4*)(ap + o);
        f32x4 a1 = *(const f32x4*)(ap + o + 4);
        s16x8 b0 = *(const s16x8*)(bp0 + o);   // single 16 B L2-hit load
        s16x8 b1 = *(const s16x8*)(bp1 + o);
        s16x8 b2 = *(const s16x8*)(bp2 + o);
        s16x8 b3 = *(const s16x8*)(bp3 + o);
        s16x8 a;
#pragma unroll
        for (int j = 0; j < 4; ++j) { a[j] = f2bf(a0[j]); a[4 + j] = f2bf(a1[j]); }
        acc0 = __builtin_amdgcn_mfma_f32_16x16x32_bf16(a, b0, acc0, 0, 0, 0);
        acc1 = __builtin_amdgcn_mfma_f32_16x16x32_bf16(a, b1, acc1, 0, 0, 0);
        acc2 = __builtin_amdgcn_mfma_f32_16x16x32_bf16(a, b2, acc2, 0, 0, 0);
        acc3 = __builtin_amdgcn_mfma_f32_16x16x32_bf16(a, b3, acc3, 0, 0, 0);
    }

    // Cross-wave (split-K) reduction. C/D: row = quad*4+reg, col = lane&15.
    __shared__ float red[4][16][N_DIM + 1];
    const int r0 = quad << 2;
#pragma unroll
    for (int r = 0; r < 4; ++r) {
        red[wave][r0 + r][l16     ] = acc0[r];
        red[wave][r0 + r][l16 + 16] = acc1[r];
        red[wave][r0 + r][l16 + 32] = acc2[r];
        red[wave][r0 + r][l16 + 48] = acc3[r];
    }
    __syncthreads();

    const int c   = tid & 63;                 // output col, coalesced store
    const int rr0 = tid >> 6;                 // rows rr0, rr0+4, rr0+8, rr0+12
    const float bias = bv[c];
#pragma unroll
    for (int i = 0; i < 4; ++i) {
        const int r = rr0 + (i << 2);
        const float s = red[0][r][c] + red[1][r][c] + red[2][r][c]
                      + red[3][r][c] + bias;
        out[((mt << 4) + r) * N_DIM + c] = s;
    }
}

extern "C" void kernel_launch(void* const* d_in, const int* in_sizes, int n_in,
                              void* d_out, int out_size, void* d_ws, size_t ws_size,
                              hipStream_t stream) {
    // dict order: 0:x 1:Wq 2:bq 3:Wk 4:bk 5:Wv 6:bv (size-checked for safety).
    int ix = 0, iw = -1, ib = -1;
    for (int i = 0; i < n_in; ++i) {
        if      (in_sizes[i] == 8388608) ix = i;
        else if (in_sizes[i] == 65536)   iw = i;   // keeps last (= Wv)
        else if (in_sizes[i] == 64)      ib = i;   // keeps last (= bv)
    }
    if (iw < 0) iw = 5;
    if (ib < 0) ib = 6;

    const float* x  = (const float*)d_in[ix];
    const float* Wv = (const float*)d_in[iw];
    const float* bv = (const float*)d_in[ib];
    short* wbf = (short*)d_ws;                 // 128 KB scratch
    float* out = (float*)d_out;

    cvt_w_kernel<<<64, 256, 0, stream>>>(Wv, wbf);
    vproj_kernel<<<512, 256, 0, stream>>>(x, wbf, bv, out);
}